// Round 7
// baseline (9.896 us; speedup 1.0000x reference)
//
#include <hip/hip_runtime.h>
#include <hip/hip_bf16.h>

// out[l,m,p,o] = sum_{k,j,i} w[k,j,l,m,i] * s[2*(l+k-1)+j, p, (o+i-2) mod 56]
//   s[c,p,q] = x[c,p,q] + x[c+64,p,q]
//   contribution valid iff 0 <= l+k-1 < 32 and 0 <= o+i-1 < 56
// final[l*4+m, (p+1)%56, o] = out[l,m,p,o]
//
// R7: 4 outputs/thread via float4. Per (ch,half) two ALIGNED float4 loads:
//   A = cols 4*o4-4 .. 4*o4-1   (o4==0 -> cols 52..55, which IS the roll wrap)
//   B = cols 4*o4   .. 4*o4+3
// cover every q needed by outputs o = 4*o4+t, t=0..3:
//   v2(t) = sB[t];  v1 = [sA.w, sB.x, sB.y, sB.z];  v0 = [sA.z, sA.w, sB.x, sB.y]
// masks: v0 zeroed at o==0 (o4==0,t=0); v2 zeroed at o==55 (o4==13,t=3).
// Grid 256 wgs (1/CU) x 448 threads; total VMEM instrs ~6x lower than R5.
__global__ __launch_bounds__(448) void fused_unfold_einsum(
    const float* __restrict__ x,   // (128, 56, 56)
    const float* __restrict__ w,   // (3, 2, 32, 4, 3)
    float* __restrict__ out)       // (128, 56, 56)
{
    const int ph = blockIdx.x;          // 0..1  (p halves of 28)
    const int c  = blockIdx.y;          // 0..127 = l*4+m (uniform)
    const int l  = c >> 2;
    const int m  = c & 3;
    const int o4 = threadIdx.x;         // 0..13 (float4 column group)
    const int po = threadIdx.y;         // 0..31, active < 28
    if (po >= 28) return;               // no barriers -> safe early exit
    const int p  = ph * 28 + po;        // 0..55

    const int colA = (o4 == 0) ? 52 : (o4 * 4 - 4);
    const int colB = o4 * 4;
    const bool mask0 = (o4 == 0);       // o==0: v0 invalid
    const bool maskW = (o4 == 13);      // o==55: v2 invalid

    float ax = 0.f, ay = 0.f, az = 0.f, aw = 0.f;

    #pragma unroll
    for (int ch = 0; ch < 6; ++ch) {
        int lsrc = l - 1 + (ch >> 1);                // uniform
        const bool chok = ((unsigned)lsrc < 32u);    // uniform
        lsrc = chok ? lsrc : 0;                      // clamp address only

        const float* __restrict__ r0 = x + (2 * lsrc + (ch & 1)) * 3136 + p * 56;
        const float* __restrict__ r1 = r0 + 64 * 3136;

        const float4 a0 = *(const float4*)(r0 + colA);
        const float4 a1 = *(const float4*)(r1 + colA);
        const float4 b0 = *(const float4*)(r0 + colB);
        const float4 b1 = *(const float4*)(r1 + colB);

        const float sAz = mask0 ? 0.f : (a0.z + a1.z);   // only used as v0(t=0)
        const float sAw = a0.w + a1.w;                   // col 4o4-1 (or wrap 55)
        const float sBx = b0.x + b1.x;
        const float sBy = b0.y + b1.y;
        const float sBz = b0.z + b1.z;
        const float sBw_raw = b0.w + b1.w;
        const float sBw = maskW ? 0.f : sBw_raw;         // only used as v2(t=3)

        // w[k,j,l,m,i] at ((ch)*32 + l)*12 + m*3 + i  (uniform -> s_load)
        const float* wp = w + (ch * 32 + l) * 12 + m * 3;
        const float w0 = chok ? wp[0] : 0.f;             // scalar cselect
        const float w1 = chok ? wp[1] : 0.f;
        const float w2 = chok ? wp[2] : 0.f;

        ax = fmaf(w0, sAz, fmaf(w1, sAw, fmaf(w2, sBx, ax)));
        ay = fmaf(w0, sAw, fmaf(w1, sBx, fmaf(w2, sBy, ay)));
        az = fmaf(w0, sBx, fmaf(w1, sBy, fmaf(w2, sBz, az)));
        aw = fmaf(w0, sBy, fmaf(w1, sBz, fmaf(w2, sBw, aw)));
    }

    const int p_out = (p + 1 == 56) ? 0 : (p + 1);
    float4 res = make_float4(ax, ay, az, aw);
    *(float4*)(out + (c * 56 + p_out) * 56 + colB) = res;
}

extern "C" void kernel_launch(void* const* d_in, const int* in_sizes, int n_in,
                              void* d_out, int out_size, void* d_ws, size_t ws_size,
                              hipStream_t stream) {
    const float* x = (const float*)d_in[0];
    const float* w = (const float*)d_in[1];
    float* out = (float*)d_out;

    dim3 grid(2, 128);     // 256 workgroups = 1 per CU
    dim3 block(14, 32);    // 448 threads = 7 waves; (o4, p-row), po<28 active
    fused_unfold_einsum<<<grid, block, 0, stream>>>(x, w, out);
}

// Round 8
// 9.824 us; speedup vs baseline: 1.0074x; 1.0074x over previous
//
#include <hip/hip_runtime.h>
#include <hip/hip_bf16.h>

// out[l,m,p,o] = sum_{k,j,i} w[k,j,l,m,i] * s[2*(l+k-1)+j, p, (o+i-2) mod 56]
//   s[c,p,q] = x[c,p,q] + x[c+64,p,q]
//   contribution valid iff 0 <= l+k-1 < 32 and 0 <= o+i-1 < 56
// final[l*4+m, (p+1)%56, o] = out[l,m,p,o]
//
// FINAL (R6 structure, best measured 9.65 us): direct loads, no LDS, no
// barriers; 512-thread blocks (8 waves) -> 896 workgroups, 7168 waves (28/CU).
// Measured floor is ~7 us fixed launch/graph-replay overhead + ~2-3 us exec;
// seven structurally different kernels all land 9.6-9.9 us.
__global__ __launch_bounds__(512) void fused_unfold_einsum(
    const float* __restrict__ x,   // (128, 56, 56)
    const float* __restrict__ w,   // (3, 2, 32, 4, 3)
    float* __restrict__ out)       // (128, 56, 56)
{
    const int pg = blockIdx.x;          // 0..6  (8 p-rows per block)
    const int lm = blockIdx.y;          // 0..127
    const int l  = lm >> 2;             // 0..31 (uniform)
    const int m  = lm & 3;              // 0..3  (uniform)
    const int tid  = threadIdx.x;
    const int lane = tid & 63;
    const int po   = tid >> 6;          // 0..7 (wave-uniform)
    const int p    = pg * 8 + po;       // 0..55

    const int o  = (lane < 56) ? lane : 55;   // dup lanes 56..63, masked at store

    // source columns with the q-roll folded in (all are valid addresses):
    const int q2 = o;                          // i=2 (valid o <= 54)
    const int q1 = (o == 0) ? 55 : o - 1;      // i=1 (always valid; o==0 wraps)
    const int q0 = (o >= 2) ? o - 2 : 55;      // i=0 (valid o >= 1; o==1 wraps)
    const bool v0ok = (o >= 1);
    const bool v2ok = (o <= 54);

    float acc0 = 0.f, acc1 = 0.f, acc2 = 0.f;

    #pragma unroll
    for (int ch = 0; ch < 6; ++ch) {
        const int kk = ch >> 1;
        int lsrc = l - 1 + kk;                       // uniform
        const bool chok = ((unsigned)lsrc < 32u);    // uniform
        lsrc = chok ? lsrc : 0;                      // clamp address only

        const float* __restrict__ r0 = x + (2 * lsrc + (ch & 1)) * 3136 + p * 56;
        const float* __restrict__ r1 = r0 + 64 * 3136;

        float v0 = r0[q0] + r1[q0];
        float v1 = r0[q1] + r1[q1];
        float v2 = r0[q2] + r1[q2];
        if (!v0ok) v0 = 0.f;
        if (!v2ok) v2 = 0.f;

        // w[k,j,l,m,i] at ((ch)*32 + l)*12 + m*3 + i  (uniform -> s_load)
        const float* wp = w + (ch * 32 + l) * 12 + m * 3;
        const float w0 = chok ? wp[0] : 0.f;         // scalar cselect
        const float w1 = chok ? wp[1] : 0.f;
        const float w2 = chok ? wp[2] : 0.f;

        acc0 = fmaf(w0, v0, acc0);
        acc1 = fmaf(w1, v1, acc1);
        acc2 = fmaf(w2, v2, acc2);
    }

    if (lane < 56) {
        const int p_out = (p + 1 == 56) ? 0 : (p + 1);
        out[((l * 4 + m) * 56 + p_out) * 56 + lane] = acc0 + acc1 + acc2;
    }
}

extern "C" void kernel_launch(void* const* d_in, const int* in_sizes, int n_in,
                              void* d_out, int out_size, void* d_ws, size_t ws_size,
                              hipStream_t stream) {
    const float* x = (const float*)d_in[0];
    const float* w = (const float*)d_in[1];
    float* out = (float*)d_out;

    dim3 grid(7, 128);    // (p-groups of 8, l*4+m) -> 896 workgroups, 7168 waves
    dim3 block(512);      // 8 waves; wave = one p-row, lane = o column
    fused_unfold_einsum<<<grid, block, 0, stream>>>(x, w, out);
}